// Round 1
// baseline (985.313 us; speedup 1.0000x reference)
//
#include <hip/hip_runtime.h>

// HiPPO-LegT parallel chunked scan.
// N=256 state, L=4096 steps, BATCH=64. Chunk C=64, K=64 chunks.
// c_t = A c_{t-1} + B f_t ; out[t][b][n] = c_{t+1}[b][n]
//
// ws layout (floats):
//   P   : A^1..A^64          (64 * 65536)
//   SQ  : A^128,256,512,1024,2048 (5 * 65536)
//   Kv  : A^j B, j=0..63     (64 * 256)
//   e   : scan buffer 0      (64 * 256 * 64)
//   w2  : scan buffer 1      (64 * 256 * 64)
// total ~26.5 MB

#define MATF 65536

// ---------- batched 256x256x256 GEMM: Z[g] = X @ Y[g] ----------
__global__ __launch_bounds__(256) void gemm_nn_batch(
    const float* __restrict__ X, const float* __restrict__ Ys,
    float* __restrict__ Zs, int count)
{
  int g    = blockIdx.x >> 4;
  int tile = blockIdx.x & 15;
  if (g >= count) return;
  const float* Y = Ys + (size_t)g * MATF;
  float*       Z = Zs + (size_t)g * MATF;
  int tr = (tile >> 2) * 64;
  int tc = (tile & 3) * 64;

  __shared__ float As[64][33];
  __shared__ float Bs[32][65];
  int tid = threadIdx.x;
  int tx = tid & 15, ty = tid >> 4;
  float acc[4][4] = {};

  for (int k0 = 0; k0 < 256; k0 += 32) {
#pragma unroll
    for (int p = 0; p < 2; ++p) {
      int idx = tid + p * 256;
      int r = idx >> 3, c4 = (idx & 7) * 4;
      float4 v = *(const float4*)(X + (size_t)(tr + r) * 256 + k0 + c4);
      As[r][c4 + 0] = v.x; As[r][c4 + 1] = v.y; As[r][c4 + 2] = v.z; As[r][c4 + 3] = v.w;
    }
#pragma unroll
    for (int p = 0; p < 2; ++p) {
      int idx = tid + p * 256;
      int r = idx >> 4, c4 = (idx & 15) * 4;
      float4 v = *(const float4*)(Y + (size_t)(k0 + r) * 256 + tc + c4);
      Bs[r][c4 + 0] = v.x; Bs[r][c4 + 1] = v.y; Bs[r][c4 + 2] = v.z; Bs[r][c4 + 3] = v.w;
    }
    __syncthreads();
#pragma unroll
    for (int kk = 0; kk < 32; ++kk) {
      float a[4], b[4];
#pragma unroll
      for (int u = 0; u < 4; ++u) a[u] = As[ty * 4 + u][kk];
#pragma unroll
      for (int v = 0; v < 4; ++v) b[v] = Bs[kk][tx * 4 + v];
#pragma unroll
      for (int u = 0; u < 4; ++u)
#pragma unroll
        for (int v = 0; v < 4; ++v) acc[u][v] += a[u] * b[v];
    }
    __syncthreads();
  }
#pragma unroll
  for (int u = 0; u < 4; ++u)
#pragma unroll
    for (int v = 0; v < 4; ++v)
      Z[(size_t)(tr + ty * 4 + u) * 256 + tc + tx * 4 + v] = acc[u][v];
}

// ---------- Kv[j] = A^j B (j=0..63) ----------
__global__ __launch_bounds__(256) void kv_kernel(
    const float* __restrict__ P, const float* __restrict__ Bv,
    float* __restrict__ Kv)
{
  int j = blockIdx.x;
  int n = threadIdx.x;
  __shared__ float bs[256];
  bs[n] = Bv[n];
  __syncthreads();
  if (j == 0) { Kv[n] = bs[n]; return; }
  const float* M = P + (size_t)(j - 1) * MATF;
  float acc = 0.f;
  for (int m = 0; m < 256; ++m) acc += M[(size_t)n * 256 + m] * bs[m];
  Kv[(size_t)j * 256 + n] = acc;
}

// ---------- local causal conv within each chunk + chunk-end states ----------
// grid: 4096 = (chunk k)*64 + batch b ; block 256 (thread = state index n)
__global__ __launch_bounds__(256) void conv_kernel(
    const float* __restrict__ in, const float* __restrict__ Kv,
    float* __restrict__ out, float* __restrict__ e)
{
  int k = blockIdx.x >> 6;
  int b = blockIdx.x & 63;
  int n = threadIdx.x;
  __shared__ float fs[64];
  if (threadIdx.x < 64)
    fs[threadIdx.x] = in[(size_t)(k * 64 + threadIdx.x) * 64 + b];
  __syncthreads();

  float f[64], kv[64];
#pragma unroll
  for (int j = 0; j < 64; ++j) {
    f[j]  = fs[j];
    kv[j] = Kv[(size_t)j * 256 + n];
  }
  float acc = 0.f;
#pragma unroll
  for (int i = 0; i < 64; ++i) {
    acc = 0.f;
#pragma unroll
    for (int j = 0; j <= i; ++j) acc += kv[j] * f[i - j];
    out[((size_t)(k * 64 + i) * 64 + b) * 256 + n] = acc;
  }
  // chunk-local end state e_k[n][b]
  e[((size_t)k * 256 + n) * 64 + b] = acc;
}

// ---------- Hillis-Steele weighted scan round ----------
// w_out[k] = w_in[k] + (k>=d ? M @ w_in[k-d] : 0) ; state is [n][b] (256x64)
__global__ __launch_bounds__(256) void scan_kernel(
    const float* __restrict__ win, float* __restrict__ wout,
    const float* __restrict__ M, int d)
{
  int k  = blockIdx.x >> 2;
  int rt = blockIdx.x & 3;
  int tid = threadIdx.x;
  const float* src = win  + (size_t)k * 16384;
  float*       dst = wout + (size_t)k * 16384;
  if (k < d) {
#pragma unroll
    for (int p = 0; p < 16; ++p) {
      int idx = rt * 4096 + p * 256 + tid;
      dst[idx] = src[idx];
    }
    return;
  }
  const float* v = win + (size_t)(k - d) * 16384;
  __shared__ float Ms[64][33];
  __shared__ float Vs[32][65];
  int tx = tid & 15, ty = tid >> 4;
  float acc[4][4] = {};
  for (int k0 = 0; k0 < 256; k0 += 32) {
#pragma unroll
    for (int p = 0; p < 2; ++p) {
      int idx = tid + p * 256;
      int r = idx >> 3, c4 = (idx & 7) * 4;
      float4 t4 = *(const float4*)(M + (size_t)(rt * 64 + r) * 256 + k0 + c4);
      Ms[r][c4 + 0] = t4.x; Ms[r][c4 + 1] = t4.y; Ms[r][c4 + 2] = t4.z; Ms[r][c4 + 3] = t4.w;
    }
#pragma unroll
    for (int p = 0; p < 2; ++p) {
      int idx = tid + p * 256;
      int r = idx >> 4, c4 = (idx & 15) * 4;
      float4 t4 = *(const float4*)(v + (size_t)(k0 + r) * 64 + c4);
      Vs[r][c4 + 0] = t4.x; Vs[r][c4 + 1] = t4.y; Vs[r][c4 + 2] = t4.z; Vs[r][c4 + 3] = t4.w;
    }
    __syncthreads();
#pragma unroll
    for (int kk = 0; kk < 32; ++kk) {
      float a[4], b[4];
#pragma unroll
      for (int u = 0; u < 4; ++u) a[u] = Ms[ty * 4 + u][kk];
#pragma unroll
      for (int v2 = 0; v2 < 4; ++v2) b[v2] = Vs[kk][tx * 4 + v2];
#pragma unroll
      for (int u = 0; u < 4; ++u)
#pragma unroll
        for (int v2 = 0; v2 < 4; ++v2) acc[u][v2] += a[u] * b[v2];
    }
    __syncthreads();
  }
#pragma unroll
  for (int u = 0; u < 4; ++u)
#pragma unroll
    for (int v2 = 0; v2 < 4; ++v2) {
      int idx = (rt * 64 + ty * 4 + u) * 64 + tx * 4 + v2;
      dst[idx] = src[idx] + acc[u][v2];
    }
}

// ---------- fix-up: out[t=k*64+i-1] += A^i @ s_k  (s_k = w[k-1]) ----------
// grid: ((k-1)*64 + (i-1))*4 + ntile ; k=1..63, i=1..64, ntile=0..3
__global__ __launch_bounds__(256) void fixup_kernel(
    const float* __restrict__ P, const float* __restrict__ w,
    float* __restrict__ out)
{
  int bid = blockIdx.x;
  int nt = bid & 3; bid >>= 2;
  int i  = (bid & 63) + 1;
  int k  = (bid >> 6) + 1;
  const float* Pi = P + (size_t)(i - 1) * MATF;
  const float* s  = w + (size_t)(k - 1) * 16384;
  int t = k * 64 + i - 1;
  float* outrow = out + (size_t)t * 16384;

  __shared__ float Ms[64][33];
  __shared__ float Ss[32][65];
  __shared__ float Ts[64][65];

  int tid = threadIdx.x;
  int tx = tid & 15, ty = tid >> 4;
  float acc[4][4] = {};
  for (int k0 = 0; k0 < 256; k0 += 32) {
#pragma unroll
    for (int p = 0; p < 2; ++p) {
      int idx = tid + p * 256;
      int r = idx >> 3, c4 = (idx & 7) * 4;
      float4 t4 = *(const float4*)(Pi + (size_t)(nt * 64 + r) * 256 + k0 + c4);
      Ms[r][c4 + 0] = t4.x; Ms[r][c4 + 1] = t4.y; Ms[r][c4 + 2] = t4.z; Ms[r][c4 + 3] = t4.w;
    }
#pragma unroll
    for (int p = 0; p < 2; ++p) {
      int idx = tid + p * 256;
      int r = idx >> 4, c4 = (idx & 15) * 4;
      float4 t4 = *(const float4*)(s + (size_t)(k0 + r) * 64 + c4);
      Ss[r][c4 + 0] = t4.x; Ss[r][c4 + 1] = t4.y; Ss[r][c4 + 2] = t4.z; Ss[r][c4 + 3] = t4.w;
    }
    __syncthreads();
#pragma unroll
    for (int kk = 0; kk < 32; ++kk) {
      float a[4], b[4];
#pragma unroll
      for (int u = 0; u < 4; ++u) a[u] = Ms[ty * 4 + u][kk];
#pragma unroll
      for (int v2 = 0; v2 < 4; ++v2) b[v2] = Ss[kk][tx * 4 + v2];
#pragma unroll
      for (int u = 0; u < 4; ++u)
#pragma unroll
        for (int v2 = 0; v2 < 4; ++v2) acc[u][v2] += a[u] * b[v2];
    }
    __syncthreads();
  }
  // acc[u][v] = D[n = nt*64+ty*4+u][b = tx*4+v]; transpose via LDS for
  // coalesced (b-major, n-contiguous) RMW into out.
#pragma unroll
  for (int u = 0; u < 4; ++u)
#pragma unroll
    for (int v2 = 0; v2 < 4; ++v2)
      Ts[ty * 4 + u][tx * 4 + v2] = acc[u][v2];
  __syncthreads();
#pragma unroll
  for (int p = 0; p < 16; ++p) {
    int b = p * 4 + (tid >> 6);
    int n = tid & 63;
    size_t oidx = (size_t)b * 256 + nt * 64 + n;
    outrow[oidx] += Ts[n][b];
  }
}

extern "C" void kernel_launch(void* const* d_in, const int* in_sizes, int n_in,
                              void* d_out, int out_size, void* d_ws, size_t ws_size,
                              hipStream_t stream)
{
  const float* in = (const float*)d_in[0];
  const float* A  = (const float*)d_in[1];
  const float* Bv = (const float*)d_in[2];
  float* out = (float*)d_out;
  float* ws  = (float*)d_ws;

  float* P  = ws;                         // A^1..A^64
  float* SQ = P  + (size_t)64 * MATF;     // A^128..A^2048
  float* Kv = SQ + (size_t)5  * MATF;     // 64*256
  float* e  = Kv + (size_t)64 * 256;      // scan buf 0
  float* w2 = e  + (size_t)64 * 16384;    // scan buf 1

  // P_1 = A
  hipMemcpyAsync(P, A, (size_t)MATF * sizeof(float),
                 hipMemcpyDeviceToDevice, stream);
  // log-doubling: P_{m+j} = P_m @ P_j, j=1..m
  for (int m = 1; m <= 32; m <<= 1) {
    gemm_nn_batch<<<dim3(m * 16), dim3(256), 0, stream>>>(
        P + (size_t)(m - 1) * MATF, P, P + (size_t)m * MATF, m);
  }
  // squarings: A^128, A^256, A^512, A^1024, A^2048
  const float* sq_src = P + (size_t)63 * MATF;
  for (int r = 0; r < 5; ++r) {
    gemm_nn_batch<<<dim3(16), dim3(256), 0, stream>>>(
        sq_src, sq_src, SQ + (size_t)r * MATF, 1);
    sq_src = SQ + (size_t)r * MATF;
  }
  kv_kernel<<<dim3(64), dim3(256), 0, stream>>>(P, Bv, Kv);
  conv_kernel<<<dim3(4096), dim3(256), 0, stream>>>(in, Kv, out, e);

  // weighted scan over chunk-end states: 6 rounds, result lands back in e
  float* bufs[2] = {e, w2};
  const float* Mptr[6] = {
      P + (size_t)63 * MATF,        // A^64
      SQ,                           // A^128
      SQ + (size_t)1 * MATF,        // A^256
      SQ + (size_t)2 * MATF,        // A^512
      SQ + (size_t)3 * MATF,        // A^1024
      SQ + (size_t)4 * MATF};       // A^2048
  for (int r = 0; r < 6; ++r) {
    scan_kernel<<<dim3(256), dim3(256), 0, stream>>>(
        bufs[r & 1], bufs[(r + 1) & 1], Mptr[r], 1 << r);
  }

  fixup_kernel<<<dim3(16128), dim3(256), 0, stream>>>(P, e, out);
}

// Round 2
// 489.883 us; speedup vs baseline: 2.0113x; 2.0113x over previous
//
#include <hip/hip_runtime.h>
#include <hip/hip_bf16.h>

// HiPPO-LegT parallel chunked scan, round 2.
// out = G @ H as one split-bf16 MFMA GEMM:
//   rows M=(k,b) 4096, cols N=(i,n) 16384, K=320 = [64 conv taps | 256 state]
//   G[(i,n)][j] = j<64 ? (j<=i ? K_{i-j}[n] : 0) : A^{i+1}[n][j-64]
//   H[(k,b)][j] = j<64 ? f[k*64+j][b]           : s_k[j-64][b]
//
// ws layout (floats):
//   P   : A^1..A^64          (64 * 65536)
//   SQ  : A^128..A^2048      (5 * 65536)
//   Kv  : A^j B, j=0..63     (64 * 256)
//   e   : scan buffer 0      (64 * 256 * 64)
//   w2  : scan buffer 1      (64 * 256 * 64)
//   Ht  : bf16 [4096][640]   (hi 0..319 | lo 320..639)   (ushort)
//   Gt  : bf16 [16384][640]                               (ushort)

#define MATF 65536

typedef __attribute__((ext_vector_type(8))) short short8;
typedef __attribute__((ext_vector_type(4))) float f32x4;

__device__ __forceinline__ unsigned short f2bf(float x) {
  union { __hip_bfloat16 h; unsigned short u; } cv;
  cv.h = __float2bfloat16(x);
  return cv.u;
}
__device__ __forceinline__ float bf2f(unsigned short u) {
  union { unsigned short u; __hip_bfloat16 h; } cv;
  cv.u = u;
  return __bfloat162float(cv.h);
}

__device__ __forceinline__ void load16_lds(const void* gsrc, void* ldst) {
  __builtin_amdgcn_global_load_lds(
      (const __attribute__((address_space(1))) unsigned int*)gsrc,
      (__attribute__((address_space(3))) unsigned int*)ldst,
      16, 0, 0);
}

// ---------- batched 256x256x256 GEMM: Z[g] = X @ Y[g] (fp32 precompute) ----------
__global__ __launch_bounds__(256) void gemm_nn_batch(
    const float* __restrict__ X, const float* __restrict__ Ys,
    float* __restrict__ Zs, int count)
{
  int g    = blockIdx.x >> 4;
  int tile = blockIdx.x & 15;
  if (g >= count) return;
  const float* Y = Ys + (size_t)g * MATF;
  float*       Z = Zs + (size_t)g * MATF;
  int tr = (tile >> 2) * 64;
  int tc = (tile & 3) * 64;

  __shared__ float As[64][33];
  __shared__ float Bs[32][65];
  int tid = threadIdx.x;
  int tx = tid & 15, ty = tid >> 4;
  float acc[4][4] = {};

  for (int k0 = 0; k0 < 256; k0 += 32) {
#pragma unroll
    for (int p = 0; p < 2; ++p) {
      int idx = tid + p * 256;
      int r = idx >> 3, c4 = (idx & 7) * 4;
      float4 v = *(const float4*)(X + (size_t)(tr + r) * 256 + k0 + c4);
      As[r][c4 + 0] = v.x; As[r][c4 + 1] = v.y; As[r][c4 + 2] = v.z; As[r][c4 + 3] = v.w;
    }
#pragma unroll
    for (int p = 0; p < 2; ++p) {
      int idx = tid + p * 256;
      int r = idx >> 4, c4 = (idx & 15) * 4;
      float4 v = *(const float4*)(Y + (size_t)(k0 + r) * 256 + tc + c4);
      Bs[r][c4 + 0] = v.x; Bs[r][c4 + 1] = v.y; Bs[r][c4 + 2] = v.z; Bs[r][c4 + 3] = v.w;
    }
    __syncthreads();
#pragma unroll
    for (int kk = 0; kk < 32; ++kk) {
      float a[4], b[4];
#pragma unroll
      for (int u = 0; u < 4; ++u) a[u] = As[ty * 4 + u][kk];
#pragma unroll
      for (int v = 0; v < 4; ++v) b[v] = Bs[kk][tx * 4 + v];
#pragma unroll
      for (int u = 0; u < 4; ++u)
#pragma unroll
        for (int v = 0; v < 4; ++v) acc[u][v] += a[u] * b[v];
    }
    __syncthreads();
  }
#pragma unroll
  for (int u = 0; u < 4; ++u)
#pragma unroll
    for (int v = 0; v < 4; ++v)
      Z[(size_t)(tr + ty * 4 + u) * 256 + tc + tx * 4 + v] = acc[u][v];
}

// ---------- Kv[j] = A^j B ----------
__global__ __launch_bounds__(256) void kv_kernel(
    const float* __restrict__ P, const float* __restrict__ Bv,
    float* __restrict__ Kv)
{
  int j = blockIdx.x;
  int n = threadIdx.x;
  __shared__ float bs[256];
  bs[n] = Bv[n];
  __syncthreads();
  if (j == 0) { Kv[n] = bs[n]; return; }
  const float* M = P + (size_t)(j - 1) * MATF;
  float acc = 0.f;
  for (int m = 0; m < 256; ++m) acc += M[(size_t)n * 256 + m] * bs[m];
  Kv[(size_t)j * 256 + n] = acc;
}

// ---------- chunk-end local states e_k[n][b] ----------
__global__ __launch_bounds__(256) void e_kernel(
    const float* __restrict__ in, const float* __restrict__ Kv,
    float* __restrict__ e)
{
  int k = blockIdx.x >> 6;
  int b = blockIdx.x & 63;
  int n = threadIdx.x;
  __shared__ float fs[64];
  if (n < 64) fs[n] = in[(size_t)(k * 64 + n) * 64 + b];
  __syncthreads();
  float acc = 0.f;
#pragma unroll
  for (int j = 0; j < 64; ++j) acc += Kv[(size_t)j * 256 + n] * fs[63 - j];
  e[((size_t)k * 256 + n) * 64 + b] = acc;
}

// ---------- Hillis-Steele weighted scan round (fp32) ----------
__global__ __launch_bounds__(256) void scan_kernel(
    const float* __restrict__ win, float* __restrict__ wout,
    const float* __restrict__ M, int d)
{
  int k  = blockIdx.x >> 2;
  int rt = blockIdx.x & 3;
  int tid = threadIdx.x;
  const float* src = win  + (size_t)k * 16384;
  float*       dst = wout + (size_t)k * 16384;
  if (k < d) {
#pragma unroll
    for (int p = 0; p < 16; ++p) {
      int idx = rt * 4096 + p * 256 + tid;
      dst[idx] = src[idx];
    }
    return;
  }
  const float* v = win + (size_t)(k - d) * 16384;
  __shared__ float Ms[64][33];
  __shared__ float Vs[32][65];
  int tx = tid & 15, ty = tid >> 4;
  float acc[4][4] = {};
  for (int k0 = 0; k0 < 256; k0 += 32) {
#pragma unroll
    for (int p = 0; p < 2; ++p) {
      int idx = tid + p * 256;
      int r = idx >> 3, c4 = (idx & 7) * 4;
      float4 t4 = *(const float4*)(M + (size_t)(rt * 64 + r) * 256 + k0 + c4);
      Ms[r][c4 + 0] = t4.x; Ms[r][c4 + 1] = t4.y; Ms[r][c4 + 2] = t4.z; Ms[r][c4 + 3] = t4.w;
    }
#pragma unroll
    for (int p = 0; p < 2; ++p) {
      int idx = tid + p * 256;
      int r = idx >> 4, c4 = (idx & 15) * 4;
      float4 t4 = *(const float4*)(v + (size_t)(k0 + r) * 64 + c4);
      Vs[r][c4 + 0] = t4.x; Vs[r][c4 + 1] = t4.y; Vs[r][c4 + 2] = t4.z; Vs[r][c4 + 3] = t4.w;
    }
    __syncthreads();
#pragma unroll
    for (int kk = 0; kk < 32; ++kk) {
      float a[4], b[4];
#pragma unroll
      for (int u = 0; u < 4; ++u) a[u] = Ms[ty * 4 + u][kk];
#pragma unroll
      for (int v2 = 0; v2 < 4; ++v2) b[v2] = Vs[kk][tx * 4 + v2];
#pragma unroll
      for (int u = 0; u < 4; ++u)
#pragma unroll
        for (int v2 = 0; v2 < 4; ++v2) acc[u][v2] += a[u] * b[v2];
    }
    __syncthreads();
  }
#pragma unroll
  for (int u = 0; u < 4; ++u)
#pragma unroll
    for (int v2 = 0; v2 < 4; ++v2) {
      int idx = (rt * 64 + ty * 4 + u) * 64 + tx * 4 + v2;
      dst[idx] = src[idx] + acc[u][v2];
    }
}

// ---------- build Ht: [4096 rows (k,b)][hi 320 | lo 320] bf16 ----------
__global__ __launch_bounds__(320) void build_ht(
    const float* __restrict__ in, const float* __restrict__ w,
    unsigned short* __restrict__ Ht)
{
  int row = blockIdx.x;
  int k = row >> 6, b = row & 63;
  int j = threadIdx.x;
  float x;
  if (j < 64) x = in[(size_t)(k * 64 + j) * 64 + b];
  else        x = (k > 0) ? w[((size_t)(k - 1) * 256 + (j - 64)) * 64 + b] : 0.f;
  unsigned short hi = f2bf(x);
  float lo = x - bf2f(hi);
  Ht[(size_t)row * 640 + j]       = hi;
  Ht[(size_t)row * 640 + 320 + j] = f2bf(lo);
}

// ---------- build Gt: [16384 rows (i,n)][hi 320 | lo 320] bf16 ----------
__global__ __launch_bounds__(320) void build_gt(
    const float* __restrict__ P, const float* __restrict__ Kv,
    unsigned short* __restrict__ Gt)
{
  int row = blockIdx.x;
  int i = row >> 8, n = row & 255;
  int j = threadIdx.x;
  float x;
  if (j < 64) x = (j <= i) ? Kv[(size_t)(i - j) * 256 + n] : 0.f;
  else        x = P[(size_t)row * 256 + (j - 64)];
  unsigned short hi = f2bf(x);
  float lo = x - bf2f(hi);
  Gt[(size_t)row * 640 + j]       = hi;
  Gt[(size_t)row * 640 + 320 + j] = f2bf(lo);
}

// ---------- the big one: out = Ht @ Gt^T via split-bf16 MFMA ----------
// block tile: 128 M-rows (k,b) x 128 N-rows (i,n), K=320 in 10 steps of 32.
// LDS layout per tile: [128 rows][8 octets of 16B], octet o = h*4 + q
// (h: 0=hi 1=lo, q: k-octet), stored at physical p = o ^ (row&7).
__global__ __launch_bounds__(256) void out_gemm(
    const unsigned short* __restrict__ Ht,
    const unsigned short* __restrict__ Gt,
    float* __restrict__ out)
{
  __shared__ unsigned short Asm[128 * 64];  // 16 KB
  __shared__ unsigned short Bsm[128 * 64];  // 16 KB

  int bid = blockIdx.x;
  int swz = (bid & 7) * 512 + (bid >> 3);   // XCD swizzle (4096 % 8 == 0)
  int nt = swz >> 5;                        // 0..127
  int mt = swz & 31;                        // 0..31
  int mrow0 = mt * 128, nrow0 = nt * 128;

  int tid = threadIdx.x;
  int w = tid >> 6, l = tid & 63;
  int wm = w >> 1, wn = w & 1;

  char* Ab = (char*)Asm;
  char* Bb = (char*)Bsm;

  auto stage = [&](const unsigned short* src, int row0, char* lds, int k0) {
#pragma unroll
    for (int it = 0; it < 4; ++it) {
      int L = it * 4096 + tid * 16;         // linear byte offset in tile
      int row = L >> 7;
      int p = (L >> 4) & 7;
      int o = p ^ (row & 7);
      int h = o >> 2, q = o & 3;
      const void* g = src + (size_t)(row0 + row) * 640 + h * 320 + k0 + q * 8;
      void* dst = lds + (it * 4096 + w * 1024);  // wave-uniform base
      load16_lds(g, dst);
    }
  };

  stage(Ht, mrow0, Ab, 0);
  stage(Gt, nrow0, Bb, 0);

  f32x4 acc[4][4] = {};
  int rAbase = wm * 64 + (l & 15);
  int rBbase = wn * 64 + (l & 15);
  int qo = l >> 4;  // k-octet 0..3

  for (int ks = 0; ks < 10; ++ks) {
    __syncthreads();  // stage drained (syncthreads waits vmcnt 0) -> tile ready
    short8 ah[4], al[4], bh[4], bl[4];
#pragma unroll
    for (int mf = 0; mf < 4; ++mf) {
      int r = rAbase + mf * 16;
      int ph = (qo)     ^ (r & 7);
      int pl = (4 + qo) ^ (r & 7);
      ah[mf] = *(const short8*)(Ab + r * 128 + ph * 16);
      al[mf] = *(const short8*)(Ab + r * 128 + pl * 16);
    }
#pragma unroll
    for (int nf = 0; nf < 4; ++nf) {
      int r = rBbase + nf * 16;
      int ph = (qo)     ^ (r & 7);
      int pl = (4 + qo) ^ (r & 7);
      bh[nf] = *(const short8*)(Bb + r * 128 + ph * 16);
      bl[nf] = *(const short8*)(Bb + r * 128 + pl * 16);
    }
    __syncthreads();  // all waves done reading LDS (lgkmcnt drained)
    if (ks < 9) {
      stage(Ht, mrow0, Ab, (ks + 1) * 32);
      stage(Gt, nrow0, Bb, (ks + 1) * 32);
    }
#pragma unroll
    for (int mf = 0; mf < 4; ++mf)
#pragma unroll
      for (int nf = 0; nf < 4; ++nf) {
        acc[mf][nf] = __builtin_amdgcn_mfma_f32_16x16x32_bf16(ah[mf], bh[nf], acc[mf][nf], 0, 0, 0);
        acc[mf][nf] = __builtin_amdgcn_mfma_f32_16x16x32_bf16(ah[mf], bl[nf], acc[mf][nf], 0, 0, 0);
        acc[mf][nf] = __builtin_amdgcn_mfma_f32_16x16x32_bf16(al[mf], bh[nf], acc[mf][nf], 0, 0, 0);
      }
  }

  // epilogue: D rows = (k,b), cols = (i,n); C/D: col = lane&15, row = (lane>>4)*4+reg
  int Mbase = mrow0 + wm * 64 + (l >> 4) * 4;
  int Nbase = nrow0 + wn * 64 + (l & 15);
#pragma unroll
  for (int mf = 0; mf < 4; ++mf)
#pragma unroll
    for (int nf = 0; nf < 4; ++nf)
#pragma unroll
      for (int r = 0; r < 4; ++r) {
        int Mrow = Mbase + mf * 16 + r;
        int Ncol = Nbase + nf * 16;
        int k = Mrow >> 6, b = Mrow & 63;
        int i = Ncol >> 8, n = Ncol & 255;
        out[((size_t)k * 4096 + (size_t)i * 64 + b) * 256 + n] = acc[mf][nf][r];
      }
}

extern "C" void kernel_launch(void* const* d_in, const int* in_sizes, int n_in,
                              void* d_out, int out_size, void* d_ws, size_t ws_size,
                              hipStream_t stream)
{
  const float* in = (const float*)d_in[0];
  const float* A  = (const float*)d_in[1];
  const float* Bv = (const float*)d_in[2];
  float* out = (float*)d_out;
  float* ws  = (float*)d_ws;

  float* P  = ws;                          // A^1..A^64
  float* SQ = P  + (size_t)64 * MATF;      // A^128..A^2048
  float* Kv = SQ + (size_t)5  * MATF;
  float* e  = Kv + (size_t)64 * 256;       // scan buf 0
  float* w2 = e  + (size_t)64 * 16384;     // scan buf 1
  unsigned short* Ht = (unsigned short*)(w2 + (size_t)64 * 16384);
  unsigned short* Gt = Ht + (size_t)4096 * 640;

  hipMemcpyAsync(P, A, (size_t)MATF * sizeof(float),
                 hipMemcpyDeviceToDevice, stream);
  for (int m = 1; m <= 32; m <<= 1) {
    gemm_nn_batch<<<dim3(m * 16), dim3(256), 0, stream>>>(
        P + (size_t)(m - 1) * MATF, P, P + (size_t)m * MATF, m);
  }
  const float* sq_src = P + (size_t)63 * MATF;
  for (int r = 0; r < 5; ++r) {
    gemm_nn_batch<<<dim3(16), dim3(256), 0, stream>>>(
        sq_src, sq_src, SQ + (size_t)r * MATF, 1);
    sq_src = SQ + (size_t)r * MATF;
  }
  kv_kernel<<<dim3(64), dim3(256), 0, stream>>>(P, Bv, Kv);
  e_kernel<<<dim3(4096), dim3(256), 0, stream>>>(in, Kv, e);

  float* bufs[2] = {e, w2};
  const float* Mptr[6] = {
      P + (size_t)63 * MATF, SQ, SQ + (size_t)1 * MATF,
      SQ + (size_t)2 * MATF, SQ + (size_t)3 * MATF, SQ + (size_t)4 * MATF};
  for (int r = 0; r < 6; ++r) {
    scan_kernel<<<dim3(256), dim3(256), 0, stream>>>(
        bufs[r & 1], bufs[(r + 1) & 1], Mptr[r], 1 << r);
  }
  // final scan result in e; s_k (chunk-k start state) = e[k-1]

  build_ht<<<dim3(4096), dim3(320), 0, stream>>>(in, e, Ht);
  build_gt<<<dim3(16384), dim3(320), 0, stream>>>(P, Kv, Gt);

  out_gemm<<<dim3(4096), dim3(256), 0, stream>>>(Ht, Gt, out);
}